// Round 5
// baseline (54.394 us; speedup 1.0000x reference)
//
#include <hip/hip_runtime.h>

#define C_OLD 128
#define C_NEW 16
#define N_ROWS 65536
#define BATCH 8
#define BLOCKS_PER_B 256
#define ROWS_PER_BLOCK (N_ROWS / BLOCKS_PER_B)   // 256
#define THREADS 256
#define HALFWAVES (THREADS / 32)                 // 8 half-waves per block
#define ITERS (ROWS_PER_BLOCK / HALFWAVES)       // 32 rows per half-wave
#define L2E 1.44269504088896340736f

typedef float f32x4 __attribute__((ext_vector_type(4)));

// x + x[lane ^ pattern] via DPP on the VALU pipe (no DS traffic).
// CTRL: 0xB1 = quad_perm(1,0,3,2) -> xor1; 0x4E = quad_perm(2,3,0,1) -> xor2;
// 0x141 = row_half_mirror -> xor4-equiv (valid once quads are uniform);
// 0x140 = row_mirror -> xor8-equiv (valid once octets are uniform).
template <int CTRL>
__device__ __forceinline__ float dpp_xadd(float x) {
  int xi = __builtin_bit_cast(int, x);
  int yi = __builtin_amdgcn_update_dpp(xi, xi, CTRL, 0xF, 0xF, false);
  return x + __builtin_bit_cast(float, yi);
}

// Kernel A: per-row softmax over 128 classes, grouped (8:1) sums into 16,
// accumulated per block. One half-wave (32 lanes) per row: lane m loads
// float4 at elements [4m,4m+3] -- all 4 fall in group m>>1.
// __launch_bounds__(256,8): cap VGPRs at 64 so all 8 waves/SIMD are resident
// (full occupancy is what lets the fill kernels hit 6.9 TB/s on this chip).
__global__ __launch_bounds__(THREADS, 8) void grouped_partial(
    const float* __restrict__ in, float* __restrict__ part) {
  const int bid = blockIdx.x;
  const int b   = bid >> 8;                 // bid / BLOCKS_PER_B
  const int rb  = bid & (BLOCKS_PER_B - 1);
  const int tid = threadIdx.x;
  const int h   = tid >> 5;   // half-wave id: 0..7
  const int m   = tid & 31;   // lane within half-wave

  const long long row0 = (long long)b * N_ROWS + (long long)rb * ROWS_PER_BLOCK + h;
  const f32x4* __restrict__ p = (const f32x4*)(in + row0 * C_OLD) + m;
  const int strideF4 = HALFWAVES * (C_OLD / 4);   // 256 float4 = 4096 B

  float acc = 0.f;  // running grouped-prob sum for group m>>1 (dup on odd lanes)
  #pragma unroll 4
  for (int it = 0; it < ITERS; ++it) {
    f32x4 v = __builtin_nontemporal_load(p + (long long)it * strideF4);

    float e = __builtin_amdgcn_exp2f(v.x * L2E) +
              __builtin_amdgcn_exp2f(v.y * L2E) +
              __builtin_amdgcn_exp2f(v.z * L2E) +
              __builtin_amdgcn_exp2f(v.w * L2E);

    float g2 = dpp_xadd<0xB1>(e);    // pair sum = 8-class group sum
    float t  = dpp_xadd<0x4E>(g2);   // xor2
    t = dpp_xadd<0x141>(t);          // xor4-equiv (quads uniform)
    t = dpp_xadd<0x140>(t);          // xor8-equiv (octets uniform)
    t += __shfl_xor(t, 16, 32);      // final cross-16 step (single DS op)

    acc += g2 * __builtin_amdgcn_rcpf(t);
  }

  __shared__ float sacc[HALFWAVES][C_NEW];
  if ((m & 1) == 0) sacc[h][m >> 1] = acc;
  __syncthreads();

  if (tid < C_NEW) {
    float s = 0.f;
    #pragma unroll
    for (int k = 0; k < HALFWAVES; ++k) s += sacc[k][tid];
    part[bid * C_NEW + tid] = s;
  }
}

// Kernel B: reduce per-block partials, softmax(avg) & softmax(targets/100)
// per batch over 16 lanes, KL(batchmean over C_NEW), mean over batches.
__global__ __launch_bounds__(1024) void final_kl(
    const float* __restrict__ part, const float* __restrict__ targets,
    float* __restrict__ out) {
  const int tid = threadIdx.x;          // 0..1023
  const int b   = tid >> 7;             // 0..7
  const int sub = (tid >> 4) & 7;       // 0..7
  const int g   = tid & 15;             // 0..15

  float s = 0.f;
  for (int k = sub; k < BLOCKS_PER_B; k += 8)
    s += part[(b * BLOCKS_PER_B + k) * C_NEW + g];

  __shared__ float red[BATCH][8][C_NEW];
  red[b][sub][g] = s;
  __syncthreads();

  if (tid < BATCH * C_NEW) {
    const int bb = tid >> 4;
    const int gg = tid & 15;
    float sum = 0.f;
    #pragma unroll
    for (int k = 0; k < 8; ++k) sum += red[bb][k][gg];
    const float avg = sum / (float)N_ROWS;

    // softmax over 16 lanes (avg)
    float mx = avg;
    #pragma unroll
    for (int off = 1; off < 16; off <<= 1) mx = fmaxf(mx, __shfl_xor(mx, off, 16));
    float e = expf(avg - mx);
    float den = e;
    #pragma unroll
    for (int off = 1; off < 16; off <<= 1) den += __shfl_xor(den, off, 16);
    const float pr = e / den;

    // softmax over 16 lanes (targets / 100)
    const float tg = targets[bb * C_NEW + gg] * 0.01f;
    float tmx = tg;
    #pragma unroll
    for (int off = 1; off < 16; off <<= 1) tmx = fmaxf(tmx, __shfl_xor(tmx, off, 16));
    float te = expf(tg - tmx);
    float tden = te;
    #pragma unroll
    for (int off = 1; off < 16; off <<= 1) tden += __shfl_xor(tden, off, 16);
    const float tp = te / tden;

    float term = tp * (logf(tp) - logf(pr + 1e-8f));
    #pragma unroll
    for (int off = 1; off < 16; off <<= 1) term += __shfl_xor(term, off, 16);

    __shared__ float kb[BATCH];
    if (gg == 0) kb[bb] = term / (float)C_NEW;
    __syncthreads();
    if (tid == 0) {
      float tot = 0.f;
      #pragma unroll
      for (int k = 0; k < BATCH; ++k) tot += kb[k];
      out[0] = tot / (float)BATCH;
    }
  }
}

extern "C" void kernel_launch(void* const* d_in, const int* in_sizes, int n_in,
                              void* d_out, int out_size, void* d_ws, size_t ws_size,
                              hipStream_t stream) {
  const float* inputs  = (const float*)d_in[0];   // [8, 65536, 128] f32
  const float* targets = (const float*)d_in[1];   // [8, 16] f32
  float* out  = (float*)d_out;                    // scalar f32
  float* part = (float*)d_ws;                     // [2048][16] f32 partials

  const int nblocks = BATCH * BLOCKS_PER_B;       // 2048
  grouped_partial<<<nblocks, THREADS, 0, stream>>>(inputs, part);
  final_kl<<<1, 1024, 0, stream>>>(part, targets, out);
}

// Round 6
// 46.850 us; speedup vs baseline: 1.1610x; 1.1610x over previous
//
#include <hip/hip_runtime.h>

#define C_OLD 128
#define C_NEW 16
#define N_ROWS 65536
#define BATCH 8
#define BLOCKS_PER_B 256
#define NBLOCKS (BATCH * BLOCKS_PER_B)           // 2048
#define ROWS_PER_BLOCK (N_ROWS / BLOCKS_PER_B)   // 256
#define THREADS 256
#define HALFWAVES (THREADS / 32)                 // 8 half-waves per block
#define ITERS (ROWS_PER_BLOCK / HALFWAVES)       // 32 rows per half-wave
#define L2E 1.44269504088896340736f

typedef float f32x4 __attribute__((ext_vector_type(4)));

// x + x[lane ^ pattern] via DPP on the VALU pipe (no DS traffic).
// CTRL: 0xB1 = quad_perm(1,0,3,2) -> xor1; 0x4E = quad_perm(2,3,0,1) -> xor2;
// 0x141 = row_half_mirror -> xor4-equiv (valid once quads are uniform);
// 0x140 = row_mirror -> xor8-equiv (valid once octets are uniform).
template <int CTRL>
__device__ __forceinline__ float dpp_xadd(float x) {
  int xi = __builtin_bit_cast(int, x);
  int yi = __builtin_amdgcn_update_dpp(xi, xi, CTRL, 0xF, 0xF, false);
  return x + __builtin_bit_cast(float, yi);
}

// Kernel A (exact R4 config -- best measured): per-row softmax over 128
// classes, grouped (8:1) sums into 16, accumulated per block. One half-wave
// (32 lanes) per row: lane m loads float4 at [4m,4m+3], all in group m>>1.
// unroll-8 for 8 loads in flight per wave (ILP beats TLP here: R5 showed
// capping VGPRs for occupancy while dropping unroll regressed).
__global__ __launch_bounds__(THREADS) void grouped_partial(
    const float* __restrict__ in, float* __restrict__ part) {
  const int bid = blockIdx.x;
  const int b   = bid >> 8;                 // bid / BLOCKS_PER_B
  const int rb  = bid & (BLOCKS_PER_B - 1);
  const int tid = threadIdx.x;
  const int h   = tid >> 5;   // half-wave id: 0..7
  const int m   = tid & 31;   // lane within half-wave

  const long long row0 = (long long)b * N_ROWS + (long long)rb * ROWS_PER_BLOCK + h;
  const f32x4* __restrict__ p = (const f32x4*)(in + row0 * C_OLD) + m;
  const int strideF4 = HALFWAVES * (C_OLD / 4);   // 256 float4 = 4096 B

  float acc = 0.f;  // running grouped-prob sum for group m>>1 (dup on odd lanes)
  #pragma unroll 8
  for (int it = 0; it < ITERS; ++it) {
    f32x4 v = __builtin_nontemporal_load(p + (long long)it * strideF4);

    float e = __builtin_amdgcn_exp2f(v.x * L2E) +
              __builtin_amdgcn_exp2f(v.y * L2E) +
              __builtin_amdgcn_exp2f(v.z * L2E) +
              __builtin_amdgcn_exp2f(v.w * L2E);

    float g2 = dpp_xadd<0xB1>(e);    // pair sum = 8-class group sum
    float t  = dpp_xadd<0x4E>(g2);   // xor2
    t = dpp_xadd<0x141>(t);          // xor4-equiv (quads uniform)
    t = dpp_xadd<0x140>(t);          // xor8-equiv (octets uniform)
    t += __shfl_xor(t, 16, 32);      // final cross-16 step (single DS op)

    acc += g2 * __builtin_amdgcn_rcpf(t);
  }

  __shared__ float sacc[HALFWAVES][C_NEW];
  if ((m & 1) == 0) sacc[h][m >> 1] = acc;
  __syncthreads();

  if (tid < C_NEW) {
    float s = 0.f;
    #pragma unroll
    for (int k = 0; k < HALFWAVES; ++k) s += sacc[k][tid];
    part[bid * C_NEW + tid] = s;
  }
}

// Kernel B: coalesced reduction of part[2048][16] (flat idx = j*1024 + tid:
// g = tid&15 static, b = j>>2 static -- 4 KB contiguous per iteration), then
// softmax(avg) & softmax(targets/100) per batch, KL batchmean, mean.
__global__ __launch_bounds__(1024) void final_kl(
    const float* __restrict__ part, const float* __restrict__ targets,
    float* __restrict__ out) {
  const int tid = threadIdx.x;          // 0..1023

  float accB[BATCH];
  #pragma unroll
  for (int i = 0; i < BATCH; ++i) accB[i] = 0.f;
  #pragma unroll
  for (int j = 0; j < 32; ++j)
    accB[j >> 2] += part[j * 1024 + tid];

  // lanes sharing g = tid&15 within a wave: l, l^16, l^32, l^48
  #pragma unroll
  for (int bb = 0; bb < BATCH; ++bb) {
    accB[bb] += __shfl_xor(accB[bb], 16, 64);
    accB[bb] += __shfl_xor(accB[bb], 32, 64);
  }

  __shared__ float red[16][BATCH][C_NEW];   // wave, b, g  (8 KB)
  {
    const int w = tid >> 6, lane = tid & 63;
    if (lane < C_NEW) {
      #pragma unroll
      for (int bb = 0; bb < BATCH; ++bb) red[w][bb][lane] = accB[bb];
    }
  }
  __syncthreads();

  __shared__ float kb[BATCH];
  if (tid < BATCH * C_NEW) {                // 128 threads: (b,g)
    const int bb = tid >> 4, g = tid & 15;
    float sum = 0.f;
    #pragma unroll
    for (int w = 0; w < 16; ++w) sum += red[w][bb][g];
    const float avg = sum / (float)N_ROWS;

    // softmax over 16 lanes (avg)
    float mx = avg;
    #pragma unroll
    for (int off = 1; off < 16; off <<= 1) mx = fmaxf(mx, __shfl_xor(mx, off, 16));
    float e = expf(avg - mx);
    float den = e;
    #pragma unroll
    for (int off = 1; off < 16; off <<= 1) den += __shfl_xor(den, off, 16);
    const float pr = e / den;

    // softmax over 16 lanes (targets / 100)
    const float tg = targets[bb * C_NEW + g] * 0.01f;
    float tmx = tg;
    #pragma unroll
    for (int off = 1; off < 16; off <<= 1) tmx = fmaxf(tmx, __shfl_xor(tmx, off, 16));
    float te = expf(tg - tmx);
    float tden = te;
    #pragma unroll
    for (int off = 1; off < 16; off <<= 1) tden += __shfl_xor(tden, off, 16);
    const float tp = te / tden;

    float term = tp * (logf(tp) - logf(pr + 1e-8f));
    #pragma unroll
    for (int off = 1; off < 16; off <<= 1) term += __shfl_xor(term, off, 16);

    if (g == 0) kb[bb] = term / (float)C_NEW;
  }
  __syncthreads();
  if (tid == 0) {
    float tot = 0.f;
    #pragma unroll
    for (int k = 0; k < BATCH; ++k) tot += kb[k];
    out[0] = tot / (float)BATCH;
  }
}

extern "C" void kernel_launch(void* const* d_in, const int* in_sizes, int n_in,
                              void* d_out, int out_size, void* d_ws, size_t ws_size,
                              hipStream_t stream) {
  const float* inputs  = (const float*)d_in[0];   // [8, 65536, 128] f32
  const float* targets = (const float*)d_in[1];   // [8, 16] f32
  float* out  = (float*)d_out;                    // scalar f32
  float* part = (float*)d_ws;                     // [2048][16] f32 partials

  grouped_partial<<<NBLOCKS, THREADS, 0, stream>>>(inputs, part);
  final_kl<<<1, 1024, 0, stream>>>(part, targets, out);
}